// Round 3
// baseline (272.307 us; speedup 1.0000x reference)
//
#include <hip/hip_runtime.h>
#include <stdint.h>

typedef __attribute__((ext_vector_type(8))) short short8;
typedef __attribute__((ext_vector_type(4))) float floatx4;

__device__ __forceinline__ unsigned short f2b_rne(float f) {
  union { float f; unsigned u; } c; c.f = f;
  unsigned u = c.u;
  unsigned r = u + 0x7fffu + ((u >> 16) & 1u);
  return (unsigned short)(r >> 16);
}

// ---------------------------------------------------------------------------
// Weight prep: Wt[n][k] = bf16(W_seg[k][c])  (plain B^T layout, K contiguous).
// B is consumed via direct global->VGPR fragment loads (L2-resident), so no
// swizzle is needed. rows 0..255=W_val, 256..511=W_so, 512..767=W_tso,
// 768..895=W_aw, 896..1023=W_taw.  bcat[n] = concatenated biases.
// ---------------------------------------------------------------------------
__global__ void prep_weights(const float* __restrict__ Wv,  const float* __restrict__ bv,
                             const float* __restrict__ Wso, const float* __restrict__ bso,
                             const float* __restrict__ Waw, const float* __restrict__ baw,
                             const float* __restrict__ Wtso,const float* __restrict__ btso,
                             const float* __restrict__ Wtaw,const float* __restrict__ btaw,
                             unsigned short* __restrict__ Wt, float* __restrict__ bcat) {
  int n = blockIdx.x;   // 0..1023
  int k = threadIdx.x;  // 0..255
  const float* W; const float* b; int c, N;
  if (n < 256)      { W = Wv;   b = bv;   c = n;       N = 256; }
  else if (n < 512) { W = Wso;  b = bso;  c = n - 256; N = 256; }
  else if (n < 768) { W = Wtso; b = btso; c = n - 512; N = 256; }
  else if (n < 896) { W = Waw;  b = baw;  c = n - 768; N = 128; }
  else              { W = Wtaw; b = btaw; c = n - 896; N = 128; }
  Wt[n * 256 + k] = f2b_rne(W[(size_t)k * N + c]);
  if (k == 0) bcat[n] = b[c];
}

// ---------------------------------------------------------------------------
// Fused kernel, barrier-light design:
//   phase 0: stage X-tile (64x256 bf16, XOR-swizzled) -> LDS; nt 0,1 (value)
//   phase 1: stage Q-tile -> LDS;                         nt 2..5 (so, tso)
//   aw phase: weight frags direct from L2, Q frags from LDS, reg softmax.
// B fragments are loaded global->VGPR (Wt is 512 KB, L2-resident) with a
// 1-deep ping-pong prefetch; the K-loops contain NO barriers (A is read-only
// after its staging barrier). MFMA operands swapped (weights first) so each
// lane's floatx4 spans 4 consecutive output columns -> float4 stores.
// Accumulation order identical to the previous verified kernel.
// ---------------------------------------------------------------------------
__global__ __launch_bounds__(256, 3)
void fused_all(const float* __restrict__ Q, const float* __restrict__ X,
               const unsigned short* __restrict__ Wt, const float* __restrict__ bcat,
               float* __restrict__ out, int M) {
  __shared__ __align__(16) char lds[32768];   // A 64x256 bf16, swizzled

  const int tid  = threadIdx.x;
  const int lane = tid & 63;
  const int wid  = tid >> 6;
  const int lrow = lane & 15;
  const int quad = lane >> 4;
  const int mw   = (wid >> 1) * 32;   // wave's 32-row span (main)
  const int nw   = (wid & 1) * 64;    // wave's 64-col span (main)
  const int mBase = blockIdx.x * 64;

  for (int phase = 0; phase < 2; ++phase) {
    const float* A = (phase == 0) ? X : Q;
    if (phase == 1) __syncthreads();  // all waves done reading X-tile
    // ---- stage A: 64x256 fp32 -> bf16, swizzled, via regs ----
    {
      floatx4 va[16];
#pragma unroll
      for (int i = 0; i < 16; ++i) {
        int id = i * 256 + tid;
        int r = id >> 6, c4 = id & 63;
        va[i] = __builtin_nontemporal_load(
            (const floatx4*)(A + (size_t)(mBase + r) * 256 + c4 * 4));
      }
#pragma unroll
      for (int i = 0; i < 16; ++i) {
        int id = i * 256 + tid;
        int r = id >> 6, c4 = id & 63;
        int c8 = c4 >> 1, hf = c4 & 1;
        int pos = (c8 & ~7) | ((c8 ^ r) & 7);
        uint2 pk;
        pk.x = ((unsigned)f2b_rne(va[i][1]) << 16) | f2b_rne(va[i][0]);
        pk.y = ((unsigned)f2b_rne(va[i][3]) << 16) | f2b_rne(va[i][2]);
        *(uint2*)(lds + r * 512 + pos * 16 + hf * 8) = pk;
      }
    }
    __syncthreads();

    const int ntBeg = phase ? 2 : 0;
    const int ntEnd = phase ? 6 : 2;
    for (int nt = ntBeg; nt < ntEnd; ++nt) {
      const int nBase = nt * 128;
      // wave's per-lane B base: row (nBase+nw+lrow), k-chunk quad
      const unsigned short* Bw = Wt + (size_t)(nBase + nw + lrow) * 256 + quad * 8;
      floatx4 acc[2][4] = {};
      short8 bA[4][2], bB[4][2];

#define LOADB(dst, s_)                                                        \
  do {                                                                        \
    _Pragma("unroll") for (int ni = 0; ni < 4; ++ni)                          \
      _Pragma("unroll") for (int kk = 0; kk < 2; ++kk)                        \
        dst[ni][kk] = *(const short8*)(Bw + ni * 4096 + (s_) * 64 + kk * 32); \
  } while (0)

#define COMPUTE(bb, s_)                                                        \
  do {                                                                         \
    short8 af[2][2];                                                           \
    _Pragma("unroll") for (int mi = 0; mi < 2; ++mi) {                         \
      int row = mw + mi * 16 + lrow;                                           \
      _Pragma("unroll") for (int kk = 0; kk < 2; ++kk)                         \
        af[mi][kk] = *(const short8*)(                                         \
            lds + row * 512 + ((s_) * 8 + ((kk * 4 + quad) ^ (row & 7))) * 16);\
    }                                                                          \
    _Pragma("unroll") for (int kk = 0; kk < 2; ++kk)                           \
      _Pragma("unroll") for (int mi = 0; mi < 2; ++mi)                         \
        _Pragma("unroll") for (int ni = 0; ni < 4; ++ni)                       \
          acc[mi][ni] = __builtin_amdgcn_mfma_f32_16x16x32_bf16(               \
              bb[ni][kk], af[mi][kk], acc[mi][ni], 0, 0, 0);                   \
  } while (0)

      LOADB(bA, 0);
      LOADB(bB, 1); COMPUTE(bA, 0);
      LOADB(bA, 2); COMPUTE(bB, 1);
      LOADB(bB, 3); COMPUTE(bA, 2);
      COMPUTE(bB, 3);
#undef LOADB
#undef COMPUTE

      // ---- epilogue: lane holds 4 consecutive cols -> float4 stores ----
      const int seg = nt >> 1, halfn = nt & 1;
      float* O = out + (size_t)seg * ((size_t)M * 256) + halfn * 128;
#pragma unroll
      for (int ni = 0; ni < 4; ++ni) {
        floatx4 b4 = *(const floatx4*)(bcat + nBase + nw + ni * 16 + quad * 4);
#pragma unroll
        for (int mi = 0; mi < 2; ++mi) {
          int row = mBase + mw + mi * 16 + lrow;
          floatx4 v = acc[mi][ni] + b4;
          __builtin_nontemporal_store(
              v, (floatx4*)(O + (size_t)row * 256 + nw + ni * 16 + quad * 4));
        }
      }
    }
  }

  // ------------------------- aw phase -------------------------
  // Wave wid owns heads {2*wid, 2*wid+1}. Weight frags direct from L2:
  // t=0,1: caw rows 768+32*wid+{0,16}+lrow; t=2,3: taw rows 896+32*wid+...
  // Q frags from the already-staged Q LDS tile. No barriers needed.
  const unsigned short* Wc = Wt + (size_t)(768 + 32 * wid + lrow) * 256 + quad * 8;
  const unsigned short* Wtp = Wt + (size_t)(896 + 32 * wid + lrow) * 256 + quad * 8;
  floatx4 acc2[4][4] = {};
#pragma unroll
  for (int s = 0; s < 8; ++s) {              // K_STEP = 32
    short8 wa[4], qf[4];
    wa[0] = *(const short8*)(Wc + s * 32);
    wa[1] = *(const short8*)(Wc + 16 * 256 + s * 32);
    wa[2] = *(const short8*)(Wtp + s * 32);
    wa[3] = *(const short8*)(Wtp + 16 * 256 + s * 32);
#pragma unroll
    for (int qt = 0; qt < 4; ++qt) {
      int row = qt * 16 + lrow;
      int cg = s * 4 + quad;
      int pos = (cg & ~7) | ((cg ^ (row & 7)) & 7);
      qf[qt] = *(const short8*)(lds + row * 512 + pos * 16);
    }
#pragma unroll
    for (int qt = 0; qt < 4; ++qt)
#pragma unroll
      for (int t = 0; t < 4; ++t)
        acc2[qt][t] = __builtin_amdgcn_mfma_f32_16x16x32_bf16(
            wa[t], qf[qt], acc2[qt][t], 0, 0, 0);   // D[wcol][qrow]
  }

  // ---- softmax over 32 (16 caw + 16 taw) per (row, head), in registers ----
  float* awc = out + (size_t)3 * ((size_t)M * 256);
  float* awt = awc + (size_t)M * 128;
#pragma unroll
  for (int hp = 0; hp < 2; ++hp) {
    const int h = 2 * wid + hp;
    floatx4 bc = *(const floatx4*)(bcat + 768 + h * 16 + quad * 4);
    floatx4 bt = *(const floatx4*)(bcat + 896 + h * 16 + quad * 4);
#pragma unroll
    for (int qt = 0; qt < 4; ++qt) {
      float c0 = acc2[qt][hp][0] + bc[0];
      float c1 = acc2[qt][hp][1] + bc[1];
      float c2 = acc2[qt][hp][2] + bc[2];
      float c3 = acc2[qt][hp][3] + bc[3];
      float t0 = acc2[qt][2 + hp][0] + bt[0];
      float t1 = acc2[qt][2 + hp][1] + bt[1];
      float t2 = acc2[qt][2 + hp][2] + bt[2];
      float t3 = acc2[qt][2 + hp][3] + bt[3];
      float mx = fmaxf(fmaxf(fmaxf(c0, c1), fmaxf(c2, c3)),
                       fmaxf(fmaxf(t0, t1), fmaxf(t2, t3)));
      mx = fmaxf(mx, __shfl_xor(mx, 16));
      mx = fmaxf(mx, __shfl_xor(mx, 32));
      float e0 = __expf(c0 - mx), e1 = __expf(c1 - mx);
      float e2 = __expf(c2 - mx), e3 = __expf(c3 - mx);
      float f0 = __expf(t0 - mx), f1 = __expf(t1 - mx);
      float f2 = __expf(t2 - mx), f3 = __expf(t3 - mx);
      float sm = ((e0 + e1) + (e2 + e3)) + ((f0 + f1) + (f2 + f3));
      sm += __shfl_xor(sm, 16);
      sm += __shfl_xor(sm, 32);
      float inv = 1.0f / sm;
      int row = mBase + qt * 16 + lrow;
      floatx4 oc; oc[0] = e0 * inv; oc[1] = e1 * inv; oc[2] = e2 * inv; oc[3] = e3 * inv;
      floatx4 ot; ot[0] = f0 * inv; ot[1] = f1 * inv; ot[2] = f2 * inv; ot[3] = f3 * inv;
      __builtin_nontemporal_store(oc, (floatx4*)(awc + (size_t)row * 128 + h * 16 + quad * 4));
      __builtin_nontemporal_store(ot, (floatx4*)(awt + (size_t)row * 128 + h * 16 + quad * 4));
    }
  }
}

// ---------------------------------------------------------------------------
extern "C" void kernel_launch(void* const* d_in, const int* in_sizes, int n_in,
                              void* d_out, int out_size, void* d_ws, size_t ws_size,
                              hipStream_t stream) {
  const float* Q    = (const float*)d_in[0];
  const float* Xf   = (const float*)d_in[1];
  const float* Wv   = (const float*)d_in[2];
  const float* bv   = (const float*)d_in[3];
  const float* Wso  = (const float*)d_in[4];
  const float* bso  = (const float*)d_in[5];
  const float* Waw  = (const float*)d_in[6];
  const float* baw  = (const float*)d_in[7];
  const float* Wtso = (const float*)d_in[8];
  const float* btso = (const float*)d_in[9];
  const float* Wtaw = (const float*)d_in[10];
  const float* btaw = (const float*)d_in[11];
  float* out = (float*)d_out;

  unsigned short* Wt = (unsigned short*)d_ws;               // 512 KB
  float* bcat = (float*)((char*)d_ws + 1024 * 256 * 2);     // 4 KB

  int M = in_sizes[0] / 256;  // 97920

  prep_weights<<<1024, 256, 0, stream>>>(Wv, bv, Wso, bso, Waw, baw,
                                         Wtso, btso, Wtaw, btaw, Wt, bcat);

  fused_all<<<M / 64, 256, 0, stream>>>(Q, Xf, Wt, bcat, out, M);
}

// Round 4
// 194.073 us; speedup vs baseline: 1.4031x; 1.4031x over previous
//
#include <hip/hip_runtime.h>
#include <stdint.h>

#define AS1 __attribute__((address_space(1)))
#define AS3 __attribute__((address_space(3)))

typedef __attribute__((ext_vector_type(8))) short short8;
typedef __attribute__((ext_vector_type(4))) float floatx4;

__device__ __forceinline__ unsigned short f2b_rne(float f) {
  union { float f; unsigned u; } c; c.f = f;
  unsigned u = c.u;
  unsigned r = u + 0x7fffu + ((u >> 16) & 1u);
  return (unsigned short)(r >> 16);
}

// ---------------------------------------------------------------------------
// Weight prep: Wt[n][k] = bf16(W_seg[k][c])  (plain B^T layout, K contiguous).
// rows 0..255=W_val, 256..511=W_so, 512..767=W_tso, 768..895=W_aw,
// 896..1023=W_taw.  bcat[n] = concatenated biases in the same order.
// (B LDS swizzle is applied at stage time by permuting the GLOBAL source,
//  keeping the global_load_lds LDS destination linear.)
// ---------------------------------------------------------------------------
__global__ void prep_weights(const float* __restrict__ Wv,  const float* __restrict__ bv,
                             const float* __restrict__ Wso, const float* __restrict__ bso,
                             const float* __restrict__ Waw, const float* __restrict__ baw,
                             const float* __restrict__ Wtso,const float* __restrict__ btso,
                             const float* __restrict__ Wtaw,const float* __restrict__ btaw,
                             unsigned short* __restrict__ Wt, float* __restrict__ bcat) {
  int n = blockIdx.x;   // 0..1023
  int k = threadIdx.x;  // 0..255
  const float* W; const float* b; int c, N;
  if (n < 256)      { W = Wv;   b = bv;   c = n;       N = 256; }
  else if (n < 512) { W = Wso;  b = bso;  c = n - 256; N = 256; }
  else if (n < 768) { W = Wtso; b = btso; c = n - 512; N = 256; }
  else if (n < 896) { W = Waw;  b = baw;  c = n - 768; N = 128; }
  else              { W = Wtaw; b = btaw; c = n - 896; N = 128; }
  Wt[n * 256 + k] = f2b_rne(W[(size_t)k * N + c]);
  if (k == 0) bcat[n] = b[c];
}

// ---------------------------------------------------------------------------
// Fused kernel with 2-phase double-buffered B pipeline:
//   per source phase: stage A-tile (64x256 bf16, XOR-swizzled) once, then a
//   continuous K-step pipeline over all n-tiles:
//     STAGE(buf^1, t+1) ; COMPUTE(buf, t) ; vmcnt(0) ; s_barrier
//   (stage loads land during compute; one barrier per step, never a
//    stage->drain->compute serialization).
// B staged via global_load_lds, LDS linear [128 rows][64B], with the bank
// swizzle pre-applied on the global source (piece kc ^ ((row>>1)&3)).
// MFMA operands swapped (weights first): lane's floatx4 = 4 consecutive
// output columns -> float4 stores + in-register softmax for aw.
// Accumulation order identical to the verified r1 kernel.
// ---------------------------------------------------------------------------
__global__ __launch_bounds__(256, 3)
void fused_all(const float* __restrict__ Q, const float* __restrict__ X,
               const unsigned short* __restrict__ Wt, const float* __restrict__ bcat,
               float* __restrict__ out, int M) {
  __shared__ __align__(16) char lds[49152];  // [0,32768) A ; [32768,49152) B dbuf 2x8KB

  const int tid  = threadIdx.x;
  const int lane = tid & 63;
  const int wid  = tid >> 6;
  const int lrow = lane & 15;
  const int quad = lane >> 4;
  const int mw   = (wid >> 1) * 32;   // wave's 32-row span (main)
  const int nw   = (wid & 1) * 64;    // wave's 64-col span (main)
  const int mBase = blockIdx.x * 64;

#define STAGE_B(cur_, nt_, s_)                                                 \
  do {                                                                         \
    const unsigned short* Bb_ = Wt + (size_t)(nt_) * 128 * 256;                \
    _Pragma("unroll") for (int j = 0; j < 2; ++j) {                            \
      int ch = j * 256 + tid;                                                  \
      int r = ch >> 2, kc = ch & 3;                                            \
      int kcs = kc ^ ((r >> 1) & 3); /* pre-swizzled source piece */           \
      const unsigned short* src = Bb_ + (size_t)r * 256 + (s_) * 32 + kcs * 8; \
      unsigned ldsoff = 32768u + (unsigned)(cur_) * 8192u +                    \
                        (unsigned)((j * 256 + (tid & ~63)) * 16);              \
      __builtin_amdgcn_global_load_lds((const AS1 void*)src,                   \
                                       (AS3 void*)(lds + ldsoff), 16, 0, 0);   \
    }                                                                          \
  } while (0)

  for (int phase = 0; phase < 2; ++phase) {
    const float* A = (phase == 0) ? X : Q;
    // ---- stage A: 64x256 fp32 -> bf16, swizzled, via regs ----
    {
      floatx4 va[16];
#pragma unroll
      for (int i = 0; i < 16; ++i) {
        int id = i * 256 + tid;
        int r = id >> 6, c4 = id & 63;
        va[i] = *(const floatx4*)(A + (size_t)(mBase + r) * 256 + c4 * 4);
      }
#pragma unroll
      for (int i = 0; i < 16; ++i) {
        int id = i * 256 + tid;
        int r = id >> 6, c4 = id & 63;
        int c8 = c4 >> 1, hf = c4 & 1;
        int pos = (c8 & ~7) | ((c8 ^ r) & 7);
        uint2 pk;
        pk.x = ((unsigned)f2b_rne(va[i][1]) << 16) | f2b_rne(va[i][0]);
        pk.y = ((unsigned)f2b_rne(va[i][3]) << 16) | f2b_rne(va[i][2]);
        *(uint2*)(lds + r * 512 + pos * 16 + hf * 8) = pk;
      }
    }
    const int ntBase = phase ? 2 : 0;
    const int nT     = phase ? 4 : 2;
    const int T      = nT * 8;
    STAGE_B(0, ntBase, 0);      // prologue: covered by the __syncthreads drain
    __syncthreads();

    int cur = 0;
    for (int ntq = 0; ntq < nT; ++ntq) {
      const int nt = ntBase + ntq;
      floatx4 acc[2][4] = {};
      for (int s = 0; s < 8; ++s) {
        const int t = ntq * 8 + s;
        if (t + 1 < T) {
          const int nt2 = ntBase + ((t + 1) >> 3);
          const int s2  = (t + 1) & 7;
          STAGE_B(cur ^ 1, nt2, s2);
        }
        // ---- compute step t from buf[cur] ----
        short8 af[2], bfr[4];
#pragma unroll
        for (int mi = 0; mi < 2; ++mi) {
          int row = mw + mi * 16 + lrow;
          int c8 = s * 4 + quad;
          int pos = (c8 & ~7) | ((c8 ^ row) & 7);
          af[mi] = *(const short8*)(lds + row * 512 + pos * 16);
        }
#pragma unroll
        for (int ni = 0; ni < 4; ++ni) {
          int r = nw + ni * 16 + lrow;
          bfr[ni] = *(const short8*)(lds + 32768 + cur * 8192 + r * 64 +
                                     ((quad ^ ((r >> 1) & 3)) * 16));
        }
#pragma unroll
        for (int mi = 0; mi < 2; ++mi)
#pragma unroll
          for (int ni = 0; ni < 4; ++ni)
            acc[mi][ni] = __builtin_amdgcn_mfma_f32_16x16x32_bf16(
                bfr[ni], af[mi], acc[mi][ni], 0, 0, 0);  // D[ncol][qrow]
        __builtin_amdgcn_sched_barrier(0);
        asm volatile("s_waitcnt vmcnt(0)" ::: "memory");
        __builtin_amdgcn_s_barrier();
        __builtin_amdgcn_sched_barrier(0);
        cur ^= 1;
      }
      // ---- epilogue: lane holds 4 consecutive cols -> float4 stores ----
      const int seg = nt >> 1, halfn = nt & 1;
      float* O = out + (size_t)seg * ((size_t)M * 256) + halfn * 128;
#pragma unroll
      for (int ni = 0; ni < 4; ++ni) {
        floatx4 b4 = *(const floatx4*)(bcat + nt * 128 + nw + ni * 16 + quad * 4);
#pragma unroll
        for (int mi = 0; mi < 2; ++mi) {
          int row = mBase + mw + mi * 16 + lrow;
          *(floatx4*)(O + (size_t)row * 256 + nw + ni * 16 + quad * 4) =
              acc[mi][ni] + b4;
        }
      }
    }
  }
#undef STAGE_B

  // ------------------------- aw phase -------------------------
  // Wave wid owns heads {2*wid, 2*wid+1}. Weight frags direct from L2
  // (tiny: 32 loads/wave, L2-resident); Q frags from the staged Q LDS tile.
  const unsigned short* Wc  = Wt + (size_t)(768 + 32 * wid + lrow) * 256 + quad * 8;
  const unsigned short* Wtp = Wt + (size_t)(896 + 32 * wid + lrow) * 256 + quad * 8;
  floatx4 acc2[4][4] = {};
#pragma unroll
  for (int s = 0; s < 8; ++s) {              // K_STEP = 32
    short8 wa[4], qf[4];
    wa[0] = *(const short8*)(Wc + s * 32);
    wa[1] = *(const short8*)(Wc + 16 * 256 + s * 32);
    wa[2] = *(const short8*)(Wtp + s * 32);
    wa[3] = *(const short8*)(Wtp + 16 * 256 + s * 32);
#pragma unroll
    for (int qt = 0; qt < 4; ++qt) {
      int row = qt * 16 + lrow;
      int cg = s * 4 + quad;
      int pos = (cg & ~7) | ((cg ^ (row & 7)) & 7);
      qf[qt] = *(const short8*)(lds + row * 512 + pos * 16);
    }
#pragma unroll
    for (int qt = 0; qt < 4; ++qt)
#pragma unroll
      for (int t = 0; t < 4; ++t)
        acc2[qt][t] = __builtin_amdgcn_mfma_f32_16x16x32_bf16(
            wa[t], qf[qt], acc2[qt][t], 0, 0, 0);   // D[wcol][qrow]
  }

  // ---- softmax over 32 (16 caw + 16 taw) per (row, head), in registers ----
  float* awc = out + (size_t)3 * ((size_t)M * 256);
  float* awt = awc + (size_t)M * 128;
#pragma unroll
  for (int hp = 0; hp < 2; ++hp) {
    const int h = 2 * wid + hp;
    floatx4 bc = *(const floatx4*)(bcat + 768 + h * 16 + quad * 4);
    floatx4 bt = *(const floatx4*)(bcat + 896 + h * 16 + quad * 4);
#pragma unroll
    for (int qt = 0; qt < 4; ++qt) {
      float c0 = acc2[qt][hp][0] + bc[0];
      float c1 = acc2[qt][hp][1] + bc[1];
      float c2 = acc2[qt][hp][2] + bc[2];
      float c3 = acc2[qt][hp][3] + bc[3];
      float t0 = acc2[qt][2 + hp][0] + bt[0];
      float t1 = acc2[qt][2 + hp][1] + bt[1];
      float t2 = acc2[qt][2 + hp][2] + bt[2];
      float t3 = acc2[qt][2 + hp][3] + bt[3];
      float mx = fmaxf(fmaxf(fmaxf(c0, c1), fmaxf(c2, c3)),
                       fmaxf(fmaxf(t0, t1), fmaxf(t2, t3)));
      mx = fmaxf(mx, __shfl_xor(mx, 16));
      mx = fmaxf(mx, __shfl_xor(mx, 32));
      float e0 = __expf(c0 - mx), e1 = __expf(c1 - mx);
      float e2 = __expf(c2 - mx), e3 = __expf(c3 - mx);
      float f0 = __expf(t0 - mx), f1 = __expf(t1 - mx);
      float f2 = __expf(t2 - mx), f3 = __expf(t3 - mx);
      float sm = ((e0 + e1) + (e2 + e3)) + ((f0 + f1) + (f2 + f3));
      sm += __shfl_xor(sm, 16);
      sm += __shfl_xor(sm, 32);
      float inv = 1.0f / sm;
      int row = mBase + qt * 16 + lrow;
      floatx4 oc; oc[0] = e0 * inv; oc[1] = e1 * inv; oc[2] = e2 * inv; oc[3] = e3 * inv;
      floatx4 ot; ot[0] = f0 * inv; ot[1] = f1 * inv; ot[2] = f2 * inv; ot[3] = f3 * inv;
      *(floatx4*)(awc + (size_t)row * 128 + h * 16 + quad * 4) = oc;
      *(floatx4*)(awt + (size_t)row * 128 + h * 16 + quad * 4) = ot;
    }
  }
}

// ---------------------------------------------------------------------------
extern "C" void kernel_launch(void* const* d_in, const int* in_sizes, int n_in,
                              void* d_out, int out_size, void* d_ws, size_t ws_size,
                              hipStream_t stream) {
  const float* Q    = (const float*)d_in[0];
  const float* Xf   = (const float*)d_in[1];
  const float* Wv   = (const float*)d_in[2];
  const float* bv   = (const float*)d_in[3];
  const float* Wso  = (const float*)d_in[4];
  const float* bso  = (const float*)d_in[5];
  const float* Waw  = (const float*)d_in[6];
  const float* baw  = (const float*)d_in[7];
  const float* Wtso = (const float*)d_in[8];
  const float* btso = (const float*)d_in[9];
  const float* Wtaw = (const float*)d_in[10];
  const float* btaw = (const float*)d_in[11];
  float* out = (float*)d_out;

  unsigned short* Wt = (unsigned short*)d_ws;               // 512 KB
  float* bcat = (float*)((char*)d_ws + 1024 * 256 * 2);     // 4 KB

  int M = in_sizes[0] / 256;  // 97920

  prep_weights<<<1024, 256, 0, stream>>>(Wv, bv, Wso, bso, Waw, baw,
                                         Wtso, btso, Wtaw, btaw, Wt, bcat);

  fused_all<<<M / 64, 256, 0, stream>>>(Q, Xf, Wt, bcat, out, M);
}

// Round 7
// 187.298 us; speedup vs baseline: 1.4539x; 1.0362x over previous
//
#include <hip/hip_runtime.h>
#include <stdint.h>

#define AS1 __attribute__((address_space(1)))
#define AS3 __attribute__((address_space(3)))

typedef __attribute__((ext_vector_type(8))) short short8;
typedef __attribute__((ext_vector_type(4))) float floatx4;

__device__ __forceinline__ unsigned short f2b_rne(float f) {
  union { float f; unsigned u; } c; c.f = f;
  unsigned u = c.u;
  unsigned r = u + 0x7fffu + ((u >> 16) & 1u);
  return (unsigned short)(r >> 16);
}

// ---------------------------------------------------------------------------
// Weight prep: Wt[n][k] = bf16(W_seg[k][c])  (plain B^T layout, K contiguous).
// rows 0..255=W_val, 256..511=W_so, 512..767=W_tso, 768..895=W_aw,
// 896..1023=W_taw.  bcat[n] = concatenated biases in the same order.
// ---------------------------------------------------------------------------
__global__ void prep_weights(const float* __restrict__ Wv,  const float* __restrict__ bv,
                             const float* __restrict__ Wso, const float* __restrict__ bso,
                             const float* __restrict__ Waw, const float* __restrict__ baw,
                             const float* __restrict__ Wtso,const float* __restrict__ btso,
                             const float* __restrict__ Wtaw,const float* __restrict__ btaw,
                             unsigned short* __restrict__ Wt, float* __restrict__ bcat) {
  int n = blockIdx.x;   // 0..1023
  int k = threadIdx.x;  // 0..255
  const float* W; const float* b; int c, N;
  if (n < 256)      { W = Wv;   b = bv;   c = n;       N = 256; }
  else if (n < 512) { W = Wso;  b = bso;  c = n - 256; N = 256; }
  else if (n < 768) { W = Wtso; b = btso; c = n - 512; N = 256; }
  else if (n < 896) { W = Waw;  b = baw;  c = n - 768; N = 128; }
  else              { W = Wtaw; b = btaw; c = n - 896; N = 128; }
  Wt[n * 256 + k] = f2b_rne(W[(size_t)k * N + c]);
  if (k == 0) bcat[n] = b[c];
}

// ---------------------------------------------------------------------------
// Fused kernel, BARRIER-FREE K-loops via per-wave B staging.
//   Each wave owns a disjoint 32-col slice (nw32 = wid*32) of every n-tile and
//   stages its own 32x32-k B slice (2 KB, double-buffered) into its own LDS
//   region with global_load_lds; sync is the wave's own counted vmcnt.
// WAR-hazard discipline (the r5/r6 race): a DMA that overwrites an LDS
//   buffer may only be ISSUED after the buffer's ds_reads have COMPLETED.
//   Enforced by  s_waitcnt lgkmcnt(0) + sched_barrier(0)  immediately before
//   every STAGE_B that reuses a buffer (in-loop prefetch AND tile prologue).
//   The lgkmcnt(0) is free in practice (MFMA operand deps already forced it).
// Pipeline per n-tile: prologue stages w0,w1; step s: vmcnt(2) (retires w_s;
//   loads retire in-order, epilogue stores ahead only make it stricter),
//   ds_read bufs, MFMA, then fence + stage w_{s+2} into the buffer just read.
// B bank swizzle: 16B piece kc stored at kc ^ ((row>>2)&3) via permuted
//   GLOBAL source (LDS dest linear, rule #21); read at quad ^ ((lrow>>2)&3);
//   verified balanced: every bank-quad serves exactly 8 lanes.
// A-tile (64x256 bf16, XOR-swizzled) staged once per source phase.
// MFMA operands swapped (weights first): lane's floatx4 = 4 consecutive
// output columns -> float4 stores + in-register softmax for aw.
// k-accumulation order per output identical to the verified r1 kernel.
// ---------------------------------------------------------------------------
__global__ __launch_bounds__(256, 3)
void fused_all(const float* __restrict__ Q, const float* __restrict__ X,
               const unsigned short* __restrict__ Wt, const float* __restrict__ bcat,
               float* __restrict__ out, int M) {
  __shared__ __align__(16) char lds[49152];  // [0,32768) A ; [32768,49152) B: 4 waves x 2 bufs x 2KB

  const int tid  = threadIdx.x;
  const int lane = tid & 63;
  const int wid  = tid >> 6;
  const int lrow = lane & 15;
  const int quad = lane >> 4;
  const int nw32 = wid * 32;          // wave's 32-col slice of each n-tile
  const int mBase = blockIdx.x * 64;

  char* waveB = lds + 32768 + wid * 4096;   // wave's private B double-buffer
  const int bchunk = (quad ^ ((lrow >> 2) & 3)) * 16;  // swizzled read piece

#define LDS_FENCE()                                        \
  do {                                                     \
    asm volatile("s_waitcnt lgkmcnt(0)" ::: "memory");     \
    __builtin_amdgcn_sched_barrier(0);                     \
  } while (0)

  for (int phase = 0; phase < 2; ++phase) {
    const float* A = (phase == 0) ? X : Q;
    if (phase == 1) __syncthreads();  // all waves done reading X-tile
    // ---- stage A: 64x256 fp32 -> bf16, swizzled, via regs ----
    {
      floatx4 va[16];
#pragma unroll
      for (int i = 0; i < 16; ++i) {
        int id = i * 256 + tid;
        int r = id >> 6, c4 = id & 63;
        va[i] = *(const floatx4*)(A + (size_t)(mBase + r) * 256 + c4 * 4);
      }
#pragma unroll
      for (int i = 0; i < 16; ++i) {
        int id = i * 256 + tid;
        int r = id >> 6, c4 = id & 63;
        int c8 = c4 >> 1, hf = c4 & 1;
        int pos = (c8 & ~7) | ((c8 ^ r) & 7);
        uint2 pk;
        pk.x = ((unsigned)f2b_rne(va[i][1]) << 16) | f2b_rne(va[i][0]);
        pk.y = ((unsigned)f2b_rne(va[i][3]) << 16) | f2b_rne(va[i][2]);
        *(uint2*)(lds + r * 512 + pos * 16 + hf * 8) = pk;
      }
    }
    __syncthreads();   // drains vmcnt+lgkmcnt for all waves

    const int ntBase = phase ? 2 : 0;
    const int nT     = phase ? 4 : 2;
    for (int ntq = 0; ntq < nT; ++ntq) {
      const int nt = ntBase + ntq;
      // wave's B slice: rows nw32..nw32+31 of this n-tile
      const unsigned short* Bb = Wt + ((size_t)nt * 128 + nw32) * 256;
      floatx4 acc[4][2] = {};

      // per-wave stage of k-window s into buffer buf_ (2 x global_load_lds),
      // bank swizzle pre-applied on the global source piece index.
#define STAGE_B(buf_, s_)                                                     \
  do {                                                                        \
    _Pragma("unroll") for (int j = 0; j < 2; ++j) {                           \
      int ch = j * 64 + lane;                                                 \
      int r_ = ch >> 2, kc = ch & 3;                                          \
      int kcs = kc ^ ((r_ >> 2) & 3);                                         \
      const unsigned short* src = Bb + (size_t)r_ * 256 + (s_) * 32 + kcs * 8;\
      unsigned ldsoff = (unsigned)(32768 + wid * 4096 + (buf_) * 2048 +       \
                                   j * 1024);                                 \
      __builtin_amdgcn_global_load_lds((const AS1 void*)src,                  \
                                       (AS3 void*)(lds + ldsoff), 16, 0, 0);  \
    }                                                                         \
  } while (0)

      // prologue: fence against previous tile's step-6/7 reads of buf0/buf1
      LDS_FENCE();
      STAGE_B(0, 0);
      __builtin_amdgcn_sched_barrier(0);
      STAGE_B(1, 1);
      __builtin_amdgcn_sched_barrier(0);
#pragma unroll
      for (int s = 0; s < 8; ++s) {
        if (s < 7) {
          asm volatile("s_waitcnt vmcnt(2)" ::: "memory");
        } else {
          asm volatile("s_waitcnt vmcnt(0)" ::: "memory");
        }
        __builtin_amdgcn_sched_barrier(0);
        const int cur = s & 1;
        short8 af[4], bfr[2];
#pragma unroll
        for (int mi = 0; mi < 4; ++mi) {
          int row = mi * 16 + lrow;
          int c8 = s * 4 + quad;
          int pos = (c8 & ~7) | ((c8 ^ row) & 7);
          af[mi] = *(const short8*)(lds + row * 512 + pos * 16);
        }
#pragma unroll
        for (int ni = 0; ni < 2; ++ni)
          bfr[ni] = *(const short8*)(waveB + cur * 2048 +
                                     (ni * 16 + lrow) * 64 + bchunk);
#pragma unroll
        for (int mi = 0; mi < 4; ++mi)
#pragma unroll
          for (int ni = 0; ni < 2; ++ni)
            acc[mi][ni] = __builtin_amdgcn_mfma_f32_16x16x32_bf16(
                bfr[ni], af[mi], acc[mi][ni], 0, 0, 0);  // D[ncol][qrow]
        if (s + 2 < 8) {
          // WAR fence: buffer `cur`'s ds_reads must be COMPLETE before the
          // DMA that overwrites it is issued (this was the r5/r6 race).
          LDS_FENCE();
          STAGE_B(cur, s + 2);
          __builtin_amdgcn_sched_barrier(0);
        }
      }
#undef STAGE_B

      // ---- epilogue: lane holds 4 consecutive cols -> float4 stores ----
      const int seg = nt >> 1, halfn = nt & 1;
      float* O = out + (size_t)seg * ((size_t)M * 256) + halfn * 128;
#pragma unroll
      for (int ni = 0; ni < 2; ++ni) {
        floatx4 b4 = *(const floatx4*)(bcat + nt * 128 + nw32 + ni * 16 + quad * 4);
#pragma unroll
        for (int mi = 0; mi < 4; ++mi) {
          int row = mBase + mi * 16 + lrow;
          *(floatx4*)(O + (size_t)row * 256 + nw32 + ni * 16 + quad * 4) =
              acc[mi][ni] + b4;
        }
      }
    }
  }
#undef LDS_FENCE

  // ------------------------- aw phase -------------------------
  // Wave wid owns heads {2*wid, 2*wid+1}. Weight frags direct from L2
  // (tiny: 32 loads/wave); Q frags from the staged Q LDS tile. No barriers.
  const unsigned short* Wc  = Wt + (size_t)(768 + 32 * wid + lrow) * 256 + quad * 8;
  const unsigned short* Wtp = Wt + (size_t)(896 + 32 * wid + lrow) * 256 + quad * 8;
  floatx4 acc2[4][4] = {};
#pragma unroll
  for (int s = 0; s < 8; ++s) {              // K_STEP = 32
    short8 wa[4], qf[4];
    wa[0] = *(const short8*)(Wc + s * 32);
    wa[1] = *(const short8*)(Wc + 16 * 256 + s * 32);
    wa[2] = *(const short8*)(Wtp + s * 32);
    wa[3] = *(const short8*)(Wtp + 16 * 256 + s * 32);
#pragma unroll
    for (int qt = 0; qt < 4; ++qt) {
      int row = qt * 16 + lrow;
      int cg = s * 4 + quad;
      int pos = (cg & ~7) | ((cg ^ (row & 7)) & 7);
      qf[qt] = *(const short8*)(lds + row * 512 + pos * 16);
    }
#pragma unroll
    for (int qt = 0; qt < 4; ++qt)
#pragma unroll
      for (int t = 0; t < 4; ++t)
        acc2[qt][t] = __builtin_amdgcn_mfma_f32_16x16x32_bf16(
            wa[t], qf[qt], acc2[qt][t], 0, 0, 0);   // D[wcol][qrow]
  }

  // ---- softmax over 32 (16 caw + 16 taw) per (row, head), in registers ----
  float* awc = out + (size_t)3 * ((size_t)M * 256);
  float* awt = awc + (size_t)M * 128;
#pragma unroll
  for (int hp = 0; hp < 2; ++hp) {
    const int h = 2 * wid + hp;
    floatx4 bc = *(const floatx4*)(bcat + 768 + h * 16 + quad * 4);
    floatx4 bt = *(const floatx4*)(bcat + 896 + h * 16 + quad * 4);
#pragma unroll
    for (int qt = 0; qt < 4; ++qt) {
      float c0 = acc2[qt][hp][0] + bc[0];
      float c1 = acc2[qt][hp][1] + bc[1];
      float c2 = acc2[qt][hp][2] + bc[2];
      float c3 = acc2[qt][hp][3] + bc[3];
      float t0 = acc2[qt][2 + hp][0] + bt[0];
      float t1 = acc2[qt][2 + hp][1] + bt[1];
      float t2 = acc2[qt][2 + hp][2] + bt[2];
      float t3 = acc2[qt][2 + hp][3] + bt[3];
      float mx = fmaxf(fmaxf(fmaxf(c0, c1), fmaxf(c2, c3)),
                       fmaxf(fmaxf(t0, t1), fmaxf(t2, t3)));
      mx = fmaxf(mx, __shfl_xor(mx, 16));
      mx = fmaxf(mx, __shfl_xor(mx, 32));
      float e0 = __expf(c0 - mx), e1 = __expf(c1 - mx);
      float e2 = __expf(c2 - mx), e3 = __expf(c3 - mx);
      float f0 = __expf(t0 - mx), f1 = __expf(t1 - mx);
      float f2 = __expf(t2 - mx), f3 = __expf(t3 - mx);
      float sm = ((e0 + e1) + (e2 + e3)) + ((f0 + f1) + (f2 + f3));
      sm += __shfl_xor(sm, 16);
      sm += __shfl_xor(sm, 32);
      float inv = 1.0f / sm;
      int row = mBase + qt * 16 + lrow;
      floatx4 oc; oc[0] = e0 * inv; oc[1] = e1 * inv; oc[2] = e2 * inv; oc[3] = e3 * inv;
      floatx4 ot; ot[0] = f0 * inv; ot[1] = f1 * inv; ot[2] = f2 * inv; ot[3] = f3 * inv;
      *(floatx4*)(awc + (size_t)row * 128 + h * 16 + quad * 4) = oc;
      *(floatx4*)(awt + (size_t)row * 128 + h * 16 + quad * 4) = ot;
    }
  }
}

// ---------------------------------------------------------------------------
extern "C" void kernel_launch(void* const* d_in, const int* in_sizes, int n_in,
                              void* d_out, int out_size, void* d_ws, size_t ws_size,
                              hipStream_t stream) {
  const float* Q    = (const float*)d_in[0];
  const float* Xf   = (const float*)d_in[1];
  const float* Wv   = (const float*)d_in[2];
  const float* bv   = (const float*)d_in[3];
  const float* Wso  = (const float*)d_in[4];
  const float* bso  = (const float*)d_in[5];
  const float* Waw  = (const float*)d_in[6];
  const float* baw  = (const float*)d_in[7];
  const float* Wtso = (const float*)d_in[8];
  const float* btso = (const float*)d_in[9];
  const float* Wtaw = (const float*)d_in[10];
  const float* btaw = (const float*)d_in[11];
  float* out = (float*)d_out;

  unsigned short* Wt = (unsigned short*)d_ws;               // 512 KB
  float* bcat = (float*)((char*)d_ws + 1024 * 256 * 2);     // 4 KB

  int M = in_sizes[0] / 256;  // 97920

  prep_weights<<<1024, 256, 0, stream>>>(Wv, bv, Wso, bso, Waw, baw,
                                         Wtso, btso, Wtaw, btaw, Wt, bcat);

  fused_all<<<M / 64, 256, 0, stream>>>(Q, Xf, Wt, bcat, out, M);
}